// Round 7
// baseline (3122.542 us; speedup 1.0000x reference)
//
#include <hip/hip_runtime.h>
#include <cstdint>
#include <cstddef>

typedef unsigned short ushort;
typedef unsigned int uint;
typedef __attribute__((ext_vector_type(8))) short short8;
typedef __attribute__((ext_vector_type(8))) unsigned short ushort8;
typedef __attribute__((ext_vector_type(4))) float float4v;

#define DM    2048
#define INNERC 4096
#define LSEQ  4096
#define NBATCH 2
#define MROWS 8192      // NBATCH*LSEQ
#define NHH   64
#define HDD   64
#define NCHUNK 32
#define CHLEN  128
#define CROWS 8         // conv rows per block

__device__ __forceinline__ float bf2f(ushort u) {
    return __uint_as_float(((unsigned int)u) << 16);
}
__device__ __forceinline__ ushort f2bf(float f) {
    unsigned int u = __float_as_uint(f);
    unsigned int r = u + 0x7FFFu + ((u >> 16) & 1u);
    return (ushort)(r >> 16);
}

// async global->LDS 16B copy. LDS dest is wave-uniform base + lane*16.
__device__ __forceinline__ void async_cp16(const ushort* __restrict__ g, ushort* l) {
    __builtin_amdgcn_global_load_lds(
        (const __attribute__((address_space(1))) unsigned int*)g,
        (__attribute__((address_space(3))) unsigned int*)l,
        16, 0, 0);
}

// ---------------- diagnostic ----------------
__global__ void diag_kernel(float* __restrict__ out, float val) {
    if (threadIdx.x == 0 && blockIdx.x == 0) out[0] = val;
}

// ---------------- f32 -> bf16 cast (single range) ----------------
__global__ __launch_bounds__(256) void cast_bf16_kernel(
    const float* __restrict__ in, ushort* __restrict__ out, int n) {
    const int i = (blockIdx.x * 256 + threadIdx.x) * 8;
    if (i + 8 > n) return;
    const float4v a = *(const float4v*)(in + i);
    const float4v b = *(const float4v*)(in + i + 4);
    ushort8 o;
    o[0] = f2bf(a[0]); o[1] = f2bf(a[1]); o[2] = f2bf(a[2]); o[3] = f2bf(a[3]);
    o[4] = f2bf(b[0]); o[5] = f2bf(b[1]); o[6] = f2bf(b[2]); o[7] = f2bf(b[3]);
    *(ushort8*)(out + i) = o;
}

// ---------------- f32 -> bf16 cast (two ranges in one launch) ----------------
__global__ __launch_bounds__(256) void cast2_bf16_kernel(
    const float* __restrict__ in1, ushort* __restrict__ out1, int n1,
    const float* __restrict__ in2, ushort* __restrict__ out2, int n2) {
    int i = (blockIdx.x * 256 + threadIdx.x) * 8;
    const float* in;
    ushort* out;
    if (i < n1) {
        in = in1 + i; out = out1 + i;
    } else {
        const int j = i - n1;
        if (j + 8 > n2) return;
        in = in2 + j; out = out2 + j;
    }
    const float4v a = *(const float4v*)(in);
    const float4v b = *(const float4v*)(in + 4);
    ushort8 o;
    o[0] = f2bf(a[0]); o[1] = f2bf(a[1]); o[2] = f2bf(a[2]); o[3] = f2bf(a[3]);
    o[4] = f2bf(b[0]); o[5] = f2bf(b[1]); o[6] = f2bf(b[2]); o[7] = f2bf(b[3]);
    *(ushort8*)(out) = o;
}

// ---------------- bf16 bt-GEMM, 256x256 tile, BK=32, 2 blocks/CU -----------
// Out(M,N) = A(M,K) * W(N,K)^T.  512 threads = 8 waves (2M x 4N); per-wave
// output 128x64 -> acc[8][4].  LDS 64 KiB: 2 dbuf x (A 16K + B 16K), BK=32
// -> 2 blocks/CU.  Rationale (round-6 counters): per-iter wall = LDS-cyc +
// MFMA-cyc (sum, not max) -> lockstep phases serialize the two pipes; a
// second independent block per CU fills each pipe's idle segments (m114).
// Row layout: 4 granules of 16B per row; physical granule gp holds logical
// q = (gp - (row>>2)) & 3  (rotation) -> <=2-way LDS bank aliasing on both
// the linear DMA stage and the ds_read_b128 fragment reads.
// Per K-tile (32): ph1 {read af0-3,bf0-3 (8); stage A(t+1)->buf^1; bar;
// MFMA rm0-3 x cn0-3; bar}; ph2 {read af4-7 (4); stage B(t+2)->buf; bar;
// MFMA rm4-7 x cn0-3; vmcnt(2); bar}.  Stage-after-last-read: A(t)'s last
// read is ph2 -> A(t+1) staged next ph1 into the other buffer; B(t)'s last
// read is ph1 -> B(t+2) staged ph2 same buffer.  vmcnt(2) leaves only this
// ph2's B-stage outstanding => A(t+1),B(t+1) landed before next ph1 reads.
// Prologue stages A(0),B(0),B(1) (6 loads), vmcnt(2).  Last 2 tiles peeled
// (tile nt-2 gates vmcnt(0); tile nt-1 has no stages/barriers).
// EPI: 0 bf16, 1 sigmoid(acc)*Aux -> bf16 (in-place ok), 2 f32.

#define MFMA_H(RBASE) do { \
    __builtin_amdgcn_s_setprio(1); \
    _Pragma("unroll") for (int rm = 0; rm < 4; ++rm) \
    _Pragma("unroll") for (int cn = 0; cn < 4; ++cn) \
        acc[(RBASE) + rm][cn] = __builtin_amdgcn_mfma_f32_16x16x32_bf16( \
            af[(RBASE) + rm], bf[cn], acc[(RBASE) + rm][cn], 0, 0, 0); \
    __builtin_amdgcn_s_setprio(0); } while (0)

#define READ_AF03(BUF) do { \
    _Pragma("unroll") for (int rm = 0; rm < 4; ++rm) \
        af[rm] = *(const short8*)&As[BUF][offA + rm * 512]; \
    } while (0)

#define READ_AF47(BUF) do { \
    _Pragma("unroll") for (int rm = 4; rm < 8; ++rm) \
        af[rm] = *(const short8*)&As[BUF][offA + rm * 512]; \
    } while (0)

#define READ_BF(BUF) do { \
    _Pragma("unroll") for (int cn = 0; cn < 4; ++cn) \
        bf[cn] = *(const short8*)&Bs[BUF][offB + cn * 512]; \
    } while (0)

// stage one full 256x32 tile of G (A or W): 2 cp16/thread (rows tid>>2 and
// 128+(tid>>2)); then advance the per-thread source offset by +32 (next tile).
#define STAGE_T(G, OFF, LBASE) do { \
    async_cp16((G) + (OFF),        (LBASE) + tid * 8); \
    async_cp16((G) + (OFF) + k128, (LBASE) + tid * 8 + 4096); \
    (OFF) += 32; } while (0)

template <int EPI>
__global__ __launch_bounds__(512, 4) void gemm256(
    const ushort* __restrict__ Ab, const ushort* __restrict__ Wb,
    void* __restrict__ Out, const ushort* __restrict__ Aux,
    int M, int N, int K) {
    __shared__ ushort As[2][8192];
    __shared__ ushort Bs[2][8192];

    const int tid  = threadIdx.x;
    const int lane = tid & 63;
    const int w    = tid >> 6;
    const int wm   = w >> 2;          // 0..1
    const int wn   = w & 3;           // 0..3
    const int l15  = lane & 15;
    const int l4   = lane >> 4;       // 0..3  (logical K-granule q)

    // XCD-aware block swizzle (nwg divisible by 8 for all our shapes)
    const int gx   = gridDim.x;
    const int nwg  = gx * gridDim.y;
    const int orig = blockIdx.y * gx + blockIdx.x;
    const int swz  = (orig & 7) * (nwg >> 3) + (orig >> 3);
    const int row0 = (swz / gx) * 256;
    const int col0 = (swz % gx) * 256;

    const int nt = K >> 5;            // K-tiles of 32

    // LDS read base offsets (elem units).  Fragment (rm) at row
    // rA = wm*128 + rm*16 + l15, logical granule q = l4; physical
    // gp = (l4 + (rA>>2)) & 3 = (l4 + (l15>>2)) & 3  (rm,wm drop mod 4).
    const int gpr  = (l4 + (l15 >> 2)) & 3;
    const int offA = (wm * 128 + l15) * 32 + gpr * 8;
    const int offB = (wn * 64 + l15) * 32 + gpr * 8;

    // Per-thread staging source offsets.  Thread covers physical granule
    // gp = tid&3 of row tid>>2 (and +128); logical q = (gp - (row>>2)) & 3
    // with (row>>2)&3 = (tid>>4)&3 for both row halves.
    const uint kg   = (uint)((((tid & 3) - (tid >> 4)) & 3) * 8);
    const uint k128 = (uint)128 * (uint)K;
    uint oA = (uint)(row0 + (tid >> 2)) * (uint)K + kg;
    uint oW = (uint)(col0 + (tid >> 2)) * (uint)K + kg;

    float4v acc[8][4];
#pragma unroll
    for (int i2 = 0; i2 < 8; i2++)
#pragma unroll
        for (int j2 = 0; j2 < 4; j2++) {
            float4v z = {0.f, 0.f, 0.f, 0.f};
            acc[i2][j2] = z;
        }

    short8 af[8], bf[4];

    // -------- prologue: A(0), B(0), B(1); wait A0,B0 (B1 may fly)
    STAGE_T(Ab, oA, &As[0][0]);
    STAGE_T(Wb, oW, &Bs[0][0]);
    STAGE_T(Wb, oW, &Bs[1][0]);
    asm volatile("s_waitcnt vmcnt(2)" ::: "memory");
    __builtin_amdgcn_s_barrier();

    int cur = 0;
#pragma unroll 1
    for (int t = 0; t < nt - 2; ++t) {
        // ph1: reads for rm0-3 + all B; stage A(t+1) -> other buffer
        READ_AF03(cur);
        READ_BF(cur);
        STAGE_T(Ab, oA, &As[cur ^ 1][0]);
        __builtin_amdgcn_s_barrier();
        MFMA_H(0);
        __builtin_amdgcn_s_barrier();

        // ph2: reads for rm4-7; stage B(t+2) -> this buffer (B dead since ph1)
        READ_AF47(cur);
        STAGE_T(Wb, oW, &Bs[cur][0]);
        __builtin_amdgcn_s_barrier();
        MFMA_H(4);
        asm volatile("s_waitcnt vmcnt(2)" ::: "memory");  // A(t+1),B(t+1) landed
        __builtin_amdgcn_s_barrier();
        cur ^= 1;
    }

    // -------- tile nt-2: stage A(nt-1) only; drain all DMA at end
    READ_AF03(cur);
    READ_BF(cur);
    STAGE_T(Ab, oA, &As[cur ^ 1][0]);
    __builtin_amdgcn_s_barrier();
    MFMA_H(0);
    __builtin_amdgcn_s_barrier();
    READ_AF47(cur);
    __builtin_amdgcn_s_barrier();
    MFMA_H(4);
    asm volatile("s_waitcnt vmcnt(0)" ::: "memory");
    __builtin_amdgcn_s_barrier();
    cur ^= 1;

    // -------- tile nt-1: no stages, no barriers
    READ_AF03(cur);
    READ_BF(cur);
    MFMA_H(0);
    READ_AF47(cur);
    MFMA_H(4);

    // epilogue: C/D layout col = lane&15, row = (lane>>4)*4 + reg
#pragma unroll
    for (int rm = 0; rm < 8; ++rm) {
#pragma unroll
        for (int cn = 0; cn < 4; ++cn) {
            const int r0 = row0 + wm * 128 + rm * 16 + l4 * 4;
            const int cc = col0 + wn * 64 + cn * 16 + l15;
#pragma unroll
            for (int rr = 0; rr < 4; ++rr) {
                const float v = acc[rm][cn][rr];
                const size_t off = (size_t)(r0 + rr) * N + cc;
                if (EPI == 0) {
                    ((ushort*)Out)[off] = f2bf(v);
                } else if (EPI == 1) {
                    const float g = 1.0f / (1.0f + __expf(-v));
                    ((ushort*)Out)[off] = f2bf(g * bf2f(Aux[off]));
                } else {
                    ((float*)Out)[off] = v;
                }
            }
        }
    }
}

// ---------------- depthwise causal conv (K=4) + SiLU + fused dt ------------
// (round-4 version, measured ~21us)  Each block: 8 consecutive rows x 2048
// channels.  8 threads per head (aligned), dt reduce = 3 shfl_xor.
__global__ __launch_bounds__(256) void conv_silu_kernel(
    const ushort* __restrict__ proj, const float* __restrict__ cw,
    const float* __restrict__ cb, const float* __restrict__ dtw,
    const float* __restrict__ dtb, ushort* __restrict__ X,
    float* __restrict__ dt) {
    const int blk  = blockIdx.x;          // 2048 blocks
    const int half = blk & 1;
    const int tile = blk >> 1;            // 1024 tiles of 8 rows
    const int bl0  = tile * CROWS;
    const bool atStart = ((bl0 & (LSEQ - 1)) == 0);
    const int c0 = half * 2048 + threadIdx.x * 8;
    const int h  = c0 >> 6;               // head of this thread's 8 channels

    float4v w[8];
    const float4v* wp4 = (const float4v*)(cw + (size_t)c0 * 4);
#pragma unroll
    for (int t = 0; t < 8; t++) w[t] = wp4[t];
    float bias[8];
    const float4v b0 = *(const float4v*)(cb + c0);
    const float4v b1 = *(const float4v*)(cb + c0 + 4);
#pragma unroll
    for (int t = 0; t < 4; t++) { bias[t] = b0[t]; bias[t + 4] = b1[t]; }

    float dtwv[8];
    const float4v d0 = *(const float4v*)(dtw + c0);
    const float4v d1 = *(const float4v*)(dtw + c0 + 4);
#pragma unroll
    for (int t = 0; t < 4; t++) { dtwv[t] = d0[t]; dtwv[t + 4] = d1[t]; }
    const float dtbv = dtb[h];

    const size_t base = (size_t)bl0 * INNERC + c0;
    ushort8 w0, w1, w2;
    const ushort8 zz = {0, 0, 0, 0, 0, 0, 0, 0};
    if (atStart) {
        w0 = zz; w1 = zz; w2 = zz;
    } else {
        w0 = *(const ushort8*)(proj + base - 3 * (size_t)INNERC);
        w1 = *(const ushort8*)(proj + base - 2 * (size_t)INNERC);
        w2 = *(const ushort8*)(proj + base - 1 * (size_t)INNERC);
    }
#pragma unroll
    for (int r = 0; r < CROWS; r++) {
        const ushort8 cur = *(const ushort8*)(proj + base + (size_t)r * INNERC);
        ushort8 o;
        float dacc = 0.0f;
#pragma unroll
        for (int j = 0; j < 8; j++) {
            const float acc = bias[j]
                + w[j][0] * bf2f(w0[j]) + w[j][1] * bf2f(w1[j])
                + w[j][2] * bf2f(w2[j]) + w[j][3] * bf2f(cur[j]);
            const float s = acc / (1.0f + __expf(-acc));   // silu
            o[j] = f2bf(s);
            dacc += s * dtwv[j];
        }
        *(ushort8*)(X + base + (size_t)r * INNERC) = o;
        dacc += __shfl_xor(dacc, 1, 64);
        dacc += __shfl_xor(dacc, 2, 64);
        dacc += __shfl_xor(dacc, 4, 64);
        if ((threadIdx.x & 7) == 0) {
            const float z = dacc + dtbv;
            dt[(bl0 + r) * 64 + h] = (z > 20.0f) ? z : __logf(1.0f + __expf(z));
        }
        w0 = w1; w1 = w2; w2 = cur;
    }
}

// ---------------- chunked diagonal scan ----------------
__global__ __launch_bounds__(256) void scan_pass1(
    const ushort* __restrict__ X, const float* __restrict__ dt,
    const float* __restrict__ A_log, const float* __restrict__ Bv,
    float* __restrict__ sumP, float* __restrict__ sumS) {
    const int task = blockIdx.x * 4 + (threadIdx.x >> 6);
    const int p  = threadIdx.x & 63;
    const int ch = task & (NCHUNK - 1);
    const int bh = task >> 5;
    const int h  = bh & 63;
    const int b  = bh >> 6;
    const float Ac = -__expf(A_log[h * 64 + p]);
    const float Bc = Bv[h * 64 + p];
    float Pr = 1.0f, s = 0.0f;
    const int bl0 = b * LSEQ + ch * CHLEN;
#pragma unroll 4
    for (int i = 0; i < CHLEN; i++) {
        const int bl   = bl0 + i;
        const float dtv = dt[bl * 64 + h];
        const float x   = bf2f(X[(size_t)bl * INNERC + h * 64 + p]);
        const float a   = __expf(dtv * Ac);
        Pr *= a;
        s = a * s + dtv * Bc * x;
    }
    sumP[(size_t)task * 64 + p] = Pr;
    sumS[(size_t)task * 64 + p] = s;
}

__global__ __launch_bounds__(64) void scan_pass2(
    const float* __restrict__ sumP, const float* __restrict__ sumS,
    float* __restrict__ carry) {
    const int bh = blockIdx.x;
    const int p  = threadIdx.x;
    float c = 0.0f;
    for (int ch = 0; ch < NCHUNK; ch++) {
        const size_t idx = ((size_t)bh * NCHUNK + ch) * 64 + p;
        carry[idx] = c;
        c = sumP[idx] * c + sumS[idx];
    }
}

__global__ __launch_bounds__(256) void scan_pass3(
    const ushort* __restrict__ X, const float* __restrict__ dt,
    const float* __restrict__ carry,
    const float* __restrict__ A_log, const float* __restrict__ Bv,
    const float* __restrict__ Cv, const float* __restrict__ Dv,
    ushort* __restrict__ Y) {
    const int task = blockIdx.x * 4 + (threadIdx.x >> 6);
    const int p  = threadIdx.x & 63;
    const int ch = task & (NCHUNK - 1);
    const int bh = task >> 5;
    const int h  = bh & 63;
    const int b  = bh >> 6;
    const float Ac = -__expf(A_log[h * 64 + p]);
    const float Bc = Bv[h * 64 + p];
    const float Cc = Cv[h * 64 + p];
    const float Dc = Dv[h * 64 + p];
    float s = carry[(size_t)task * 64 + p];
    const int bl0 = b * LSEQ + ch * CHLEN;
#pragma unroll 2
    for (int i = 0; i < CHLEN; i++) {
        const int bl = bl0 + i;
        const size_t xoff = (size_t)bl * INNERC + h * 64 + p;
        const float dtv = dt[bl * 64 + h];
        const float x   = bf2f(X[xoff]);
        const float a   = __expf(dtv * Ac);
        s = a * s + dtv * Bc * x;
        Y[xoff] = f2bf(Cc * s + Dc * x);
    }
}

// ---------------- workspace layout (bytes) ----------------
#define OFF_PROJ  ((size_t)0)            // 67,108,864 : proj -> Y -> comb
#define OFF_HID   ((size_t)67108864)     // 33,554,432 : hidden bf16
#define OFF_WB    ((size_t)100663296)    // 16,777,216 : weight bf16 (reused 3x)
#define OFF_DT    ((size_t)117440512)    //  2,097,152
#define OFF_SUMP  ((size_t)119537664)    //  1,048,576
#define OFF_SUMS  ((size_t)120586240)    //  1,048,576
#define OFF_CARRY ((size_t)121634816)    //  1,048,576
#define WS_NEEDED ((size_t)122683392)    // = 117 MiB

extern "C" void kernel_launch(void* const* d_in, const int* in_sizes, int n_in,
                              void* d_out, int out_size, void* d_ws, size_t ws_size,
                              hipStream_t stream) {
    if (ws_size < WS_NEEDED) {
        diag_kernel<<<1, 64, 0, stream>>>((float*)d_out, (float)(ws_size >> 20));
        return;
    }
    const float* hidden = (const float*)d_in[0];
    const float* w_in   = (const float*)d_in[1];
    const float* w_gate = (const float*)d_in[2];
    const float* w_out  = (const float*)d_in[3];
    const float* conv_w = (const float*)d_in[4];
    const float* conv_b = (const float*)d_in[5];
    const float* dt_w   = (const float*)d_in[6];
    const float* dt_b   = (const float*)d_in[7];
    const float* A_log  = (const float*)d_in[8];
    const float* Bv     = (const float*)d_in[9];
    const float* Cv     = (const float*)d_in[10];
    const float* Dv     = (const float*)d_in[11];

    char* ws = (char*)d_ws;
    ushort* projbuf = (ushort*)(ws + OFF_PROJ);   // proj, then Y, then comb
    ushort* hid16   = (ushort*)(ws + OFF_HID);
    ushort* wbuf    = (ushort*)(ws + OFF_WB);
    float*  dtf     = (float*)(ws + OFF_DT);
    float*  sumP    = (float*)(ws + OFF_SUMP);
    float*  sumS    = (float*)(ws + OFF_SUMS);
    float*  carry   = (float*)(ws + OFF_CARRY);
    ushort* x16     = (ushort*)d_out;             // X scratch inside d_out

    // hidden + in_proj weight casts in one launch
    cast2_bf16_kernel<<<12288, 256, 0, stream>>>(
        hidden, hid16, MROWS * DM, w_in, wbuf, INNERC * DM);

    // in_proj GEMM -> proj (bf16)
    gemm256<0><<<dim3(INNERC / 256, MROWS / 256), 512, 0, stream>>>(
        hid16, wbuf, projbuf, nullptr, MROWS, INNERC, DM);

    // conv + silu -> X (in d_out) with fused dt
    conv_silu_kernel<<<(MROWS / CROWS) * 2, 256, 0, stream>>>(
        projbuf, conv_w, conv_b, dt_w, dt_b, x16, dtf);

    // chunked scan; pass3 writes y into projbuf (proj dead after conv)
    scan_pass1<<<(NBATCH * NHH * NCHUNK) / 4, 256, 0, stream>>>(
        x16, dtf, A_log, Bv, sumP, sumS);
    scan_pass2<<<NBATCH * NHH, 64, 0, stream>>>(sumP, sumS, carry);
    scan_pass3<<<(NBATCH * NHH * NCHUNK) / 4, 256, 0, stream>>>(
        x16, dtf, carry, A_log, Bv, Cv, Dv, projbuf);

    // gate GEMM with fused gating: comb = sigmoid(G) * Y, in-place in projbuf
    cast_bf16_kernel<<<4096, 256, 0, stream>>>(w_gate, wbuf, INNERC * DM);
    gemm256<1><<<dim3(INNERC / 256, MROWS / 256), 512, 0, stream>>>(
        hid16, wbuf, projbuf, projbuf, MROWS, INNERC, DM);

    // output projection (f32 out) — overwrites X scratch in d_out
    cast_bf16_kernel<<<4096, 256, 0, stream>>>(w_out, wbuf, DM * INNERC);
    gemm256<2><<<dim3(DM / 256, MROWS / 256), 512, 0, stream>>>(
        projbuf, wbuf, d_out, nullptr, MROWS, DM, INNERC);
}

// Round 8
// 646.844 us; speedup vs baseline: 4.8273x; 4.8273x over previous
//
#include <hip/hip_runtime.h>
#include <cstdint>
#include <cstddef>

typedef unsigned short ushort;
typedef unsigned int uint;
typedef __attribute__((ext_vector_type(8))) short short8;
typedef __attribute__((ext_vector_type(8))) unsigned short ushort8;
typedef __attribute__((ext_vector_type(4))) float float4v;

#define DM    2048
#define INNERC 4096
#define LSEQ  4096
#define NBATCH 2
#define MROWS 8192      // NBATCH*LSEQ
#define NHH   64
#define HDD   64
#define NCHUNK 32
#define CHLEN  128
#define CROWS 8         // conv rows per block

__device__ __forceinline__ float bf2f(ushort u) {
    return __uint_as_float(((unsigned int)u) << 16);
}
__device__ __forceinline__ ushort f2bf(float f) {
    unsigned int u = __float_as_uint(f);
    unsigned int r = u + 0x7FFFu + ((u >> 16) & 1u);
    return (ushort)(r >> 16);
}

// async global->LDS 16B copy. LDS dest is wave-uniform base + lane*16.
__device__ __forceinline__ void async_cp16(const ushort* __restrict__ g, ushort* l) {
    __builtin_amdgcn_global_load_lds(
        (const __attribute__((address_space(1))) unsigned int*)g,
        (__attribute__((address_space(3))) unsigned int*)l,
        16, 0, 0);
}

// ---------------- diagnostic ----------------
__global__ void diag_kernel(float* __restrict__ out, float val) {
    if (threadIdx.x == 0 && blockIdx.x == 0) out[0] = val;
}

// ---------------- f32 -> bf16 cast (single range) ----------------
__global__ __launch_bounds__(256) void cast_bf16_kernel(
    const float* __restrict__ in, ushort* __restrict__ out, int n) {
    const int i = (blockIdx.x * 256 + threadIdx.x) * 8;
    if (i + 8 > n) return;
    const float4v a = *(const float4v*)(in + i);
    const float4v b = *(const float4v*)(in + i + 4);
    ushort8 o;
    o[0] = f2bf(a[0]); o[1] = f2bf(a[1]); o[2] = f2bf(a[2]); o[3] = f2bf(a[3]);
    o[4] = f2bf(b[0]); o[5] = f2bf(b[1]); o[6] = f2bf(b[2]); o[7] = f2bf(b[3]);
    *(ushort8*)(out + i) = o;
}

// ---------------- f32 -> bf16 cast (two ranges in one launch) ----------------
__global__ __launch_bounds__(256) void cast2_bf16_kernel(
    const float* __restrict__ in1, ushort* __restrict__ out1, int n1,
    const float* __restrict__ in2, ushort* __restrict__ out2, int n2) {
    int i = (blockIdx.x * 256 + threadIdx.x) * 8;
    const float* in;
    ushort* out;
    if (i < n1) {
        in = in1 + i; out = out1 + i;
    } else {
        const int j = i - n1;
        if (j + 8 > n2) return;
        in = in2 + j; out = out2 + j;
    }
    const float4v a = *(const float4v*)(in);
    const float4v b = *(const float4v*)(in + 4);
    ushort8 o;
    o[0] = f2bf(a[0]); o[1] = f2bf(a[1]); o[2] = f2bf(a[2]); o[3] = f2bf(a[3]);
    o[4] = f2bf(b[0]); o[5] = f2bf(b[1]); o[6] = f2bf(b[2]); o[7] = f2bf(b[3]);
    *(ushort8*)(out) = o;
}

// ---------------- bf16 bt-GEMM, 256x256 tile, 8-phase counted-vmcnt ----------
// (round-6 measured-best: 145.5us @ 2048-K, MfmaUtil 41%, FETCH 182MB,
//  bank conflicts 0.  BK=64, LDS 128 KiB, 1 block/CU.)
// Out(M,N) = A(M,K) * W(N,K)^T.  512 threads = 8 waves (2M x 4N); per-wave
// output 128x64 -> acc[8][4].  Granule swizzle: 16B granule (row, q) at slot
// row*8 + (q ^ (row&7)).  ds_read addrs = base-reg + compile-time imm (XOR
// decomposed); staging via 4 per-thread 32-bit offsets advanced +64/use;
// last iteration peeled.  No blanket lgkmcnt(0) (compiler emits fine-grained
// waits).  Gates: vmcnt(4)@p4, vmcnt(8)@p8 (counted, never 0 in main loop).
// NOTE (round-7 lesson): staging width per row must be a full 128B line;
// BK<64 halves line utilization AND collapses L2/L3 reuse (FETCH 10x).
// EPI: 0 bf16, 1 sigmoid(acc)*Aux -> bf16 (in-place ok), 2 f32.

#define PH_PRE() __builtin_amdgcn_s_barrier()
#define PH_POST() __builtin_amdgcn_s_barrier()

#define MFMA_Q(AF, RBASE, CL) do { \
    __builtin_amdgcn_s_setprio(1); \
    _Pragma("unroll") for (int kk = 0; kk < 2; ++kk) \
    _Pragma("unroll") for (int rm = 0; rm < 4; ++rm) \
    _Pragma("unroll") for (int cn = 0; cn < 2; ++cn) \
        acc[(RBASE) + rm][(CL) + cn] = __builtin_amdgcn_mfma_f32_16x16x32_bf16( \
            AF[rm][kk], bf[(CL) + cn][kk], acc[(RBASE) + rm][(CL) + cn], 0, 0, 0); \
    __builtin_amdgcn_s_setprio(0); } while (0)

#define READ_A(DST, BUF, HB) do { \
    _Pragma("unroll") for (int rm = 0; rm < 4; ++rm) { \
        DST[rm][0] = *(const short8*)&As[BUF][offA_k0 + ((HB) * 4 + rm) * 1024]; \
        DST[rm][1] = *(const short8*)&As[BUF][offA_k1 + ((HB) * 4 + rm) * 1024]; \
    } } while (0)

#define READ_B2(BUF, CNLO) do { \
    _Pragma("unroll") for (int cn = 0; cn < 2; ++cn) { \
        bf[(CNLO) + cn][0] = *(const short8*)&Bs[BUF][offB_k0 + ((CNLO) + cn) * 1024]; \
        bf[(CNLO) + cn][1] = *(const short8*)&Bs[BUF][offB_k1 + ((CNLO) + cn) * 1024]; \
    } } while (0)

#define STAGE(G, OFF, LBASE) do { \
    async_cp16((G) + (OFF),       (LBASE) + (tid << 3)); \
    async_cp16((G) + (OFF) + k64, (LBASE) + (tid << 3) + 4096); \
    (OFF) += 64; } while (0)

template <int EPI>
__global__ __launch_bounds__(512, 2) void gemm256(
    const ushort* __restrict__ Ab, const ushort* __restrict__ Wb,
    void* __restrict__ Out, const ushort* __restrict__ Aux,
    int M, int N, int K) {
    __shared__ ushort As[2][16384];
    __shared__ ushort Bs[2][16384];

    const int tid  = threadIdx.x;
    const int lane = tid & 63;
    const int w    = tid >> 6;
    const int wm   = w >> 2;          // 0..1
    const int wn   = w & 3;           // 0..3
    const int l15  = lane & 15;
    const int l4   = lane >> 4;       // 0..3
    const int swz7 = l15 & 7;
    const int s01  = swz7 & 3;
    const int b2   = (swz7 >> 2) & 1;

    // XCD-aware block swizzle (nwg divisible by 8 for all our shapes)
    const int gx   = gridDim.x;
    const int nwg  = gx * gridDim.y;
    const int orig = blockIdx.y * gx + blockIdx.x;
    const int swz  = (orig & 7) * (nwg >> 3) + (orig >> 3);
    const int row0 = (swz / gx) * 256;
    const int col0 = (swz % gx) * 256;

    const int ni = K >> 7;            // iterations (2 K-tiles each)

    // precomputed LDS read base offsets (elem units)
    const int commA   = (wm * 128 + l15) * 64 + (l4 ^ s01) * 8;
    const int offA_k0 = commA + (b2 ? 32 : 0);
    const int offA_k1 = commA + (b2 ? 0 : 32);
    const int commB   = (wn * 64 + l15) * 64 + (l4 ^ s01) * 8;
    const int offB_k0 = commB + (b2 ? 32 : 0);
    const int offB_k1 = commB + (b2 ? 0 : 32);

    // precomputed per-thread staging source offsets (elem units)
    const uint rr8 = (uint)(tid >> 3);
    const uint kg8 = (uint)(((tid & 7) ^ ((tid >> 3) & 7)) * 8);
    const uint k64 = (uint)64 * (uint)K;            // 64-row stride (j=1)
    uint oA0 = (uint)(row0) * (uint)K + rr8 * (uint)K + kg8;
    uint oA1 = oA0 + (uint)128 * (uint)K;
    uint oW0 = (uint)(col0) * (uint)K + rr8 * (uint)K + kg8;
    uint oW1 = oW0 + (uint)128 * (uint)K;

    float4v acc[8][4];
#pragma unroll
    for (int i2 = 0; i2 < 8; i2++)
#pragma unroll
        for (int j2 = 0; j2 < 4; j2++) {
            float4v z = {0.f, 0.f, 0.f, 0.f};
            acc[i2][j2] = z;
        }

    short8 afL[4][2], afH[4][2], bf[4][2];

    // -------- prologue: tiles 0 (buf0) and 1 (buf1); wait tile0
    STAGE(Ab, oA0, &As[0][0]);
    STAGE(Ab, oA1, &As[0][8192]);
    STAGE(Wb, oW0, &Bs[0][0]);
    STAGE(Wb, oW1, &Bs[0][8192]);
    STAGE(Ab, oA0, &As[1][0]);
    STAGE(Ab, oA1, &As[1][8192]);
    STAGE(Wb, oW0, &Bs[1][0]);
    STAGE(Wb, oW1, &Bs[1][8192]);
    asm volatile("s_waitcnt vmcnt(8)" ::: "memory");   // tile0 landed
    __builtin_amdgcn_s_barrier();

#pragma unroll 1
    for (int i = 0; i < ni - 1; ++i) {
        // ---- p1: buf0, Q(rm0-3, cn0-1); 12 ds_reads
        READ_A(afL, 0, 0);
        READ_B2(0, 0);
        asm volatile("s_waitcnt lgkmcnt(8)");
        PH_PRE();
        MFMA_Q(afL, 0, 0);
        PH_POST();

        // ---- p2: Q(rm0-3, cn2-3)
        READ_B2(0, 2);
        PH_PRE();
        MFMA_Q(afL, 0, 2);
        PH_POST();

        // ---- p3: Q(rm4-7, cn2-3); stage (u+2).Bh0
        READ_A(afH, 0, 1);
        STAGE(Wb, oW0, &Bs[0][0]);
        PH_PRE();
        MFMA_Q(afH, 4, 2);
        PH_POST();

        // ---- p4: Q(rm4-7, cn0-1); stage (u+2).Bh1; gate buf1 (tile u+1)
        STAGE(Wb, oW1, &Bs[0][8192]);
        PH_PRE();
        MFMA_Q(afH, 4, 0);
        asm volatile("s_waitcnt vmcnt(4)" ::: "memory");
        __builtin_amdgcn_s_barrier();

        // ---- p5: buf1, Q(rm0-3, cn0-1); stage (u+2).Ah0
        READ_A(afL, 1, 0);
        READ_B2(1, 0);
        STAGE(Ab, oA0, &As[0][0]);
        asm volatile("s_waitcnt lgkmcnt(8)");
        PH_PRE();
        MFMA_Q(afL, 0, 0);
        PH_POST();

        // ---- p6: Q(rm0-3, cn2-3); stage (u+2).Ah1
        READ_B2(1, 2);
        STAGE(Ab, oA1, &As[0][8192]);
        PH_PRE();
        MFMA_Q(afL, 0, 2);
        PH_POST();

        // ---- p7: Q(rm4-7, cn2-3); stage (u+3).Bh0+Bh1
        READ_A(afH, 1, 1);
        STAGE(Wb, oW0, &Bs[1][0]);
        STAGE(Wb, oW1, &Bs[1][8192]);
        PH_PRE();
        MFMA_Q(afH, 4, 2);
        PH_POST();

        // ---- p8: Q(rm4-7, cn0-1); stage (u+3).Ah0+Ah1; gate buf0 (tile u+2)
        STAGE(Ab, oA0, &As[1][0]);
        STAGE(Ab, oA1, &As[1][8192]);
        PH_PRE();
        MFMA_Q(afH, 4, 0);
        asm volatile("s_waitcnt vmcnt(8)" ::: "memory");
        __builtin_amdgcn_s_barrier();
    }

    // -------- peeled last iteration: no stages, no intra-phase barriers
    {
        READ_A(afL, 0, 0);
        READ_B2(0, 0);
        READ_B2(0, 2);
        READ_A(afH, 0, 1);
        __builtin_amdgcn_s_setprio(1);
        MFMA_Q(afL, 0, 0);
        MFMA_Q(afL, 0, 2);
        MFMA_Q(afH, 4, 2);
        MFMA_Q(afH, 4, 0);
        __builtin_amdgcn_s_setprio(0);
        asm volatile("s_waitcnt vmcnt(0)" ::: "memory");
        __builtin_amdgcn_s_barrier();
        READ_A(afL, 1, 0);
        READ_B2(1, 0);
        READ_B2(1, 2);
        READ_A(afH, 1, 1);
        __builtin_amdgcn_s_setprio(1);
        MFMA_Q(afL, 0, 0);
        MFMA_Q(afL, 0, 2);
        MFMA_Q(afH, 4, 2);
        MFMA_Q(afH, 4, 0);
        __builtin_amdgcn_s_setprio(0);
    }

    // epilogue: C/D layout col = lane&15, row = (lane>>4)*4 + reg
#pragma unroll
    for (int rm = 0; rm < 8; ++rm) {
#pragma unroll
        for (int cn = 0; cn < 4; ++cn) {
            const int r0 = row0 + wm * 128 + rm * 16 + l4 * 4;
            const int cc = col0 + wn * 64 + cn * 16 + l15;
#pragma unroll
            for (int rr = 0; rr < 4; ++rr) {
                const float v = acc[rm][cn][rr];
                const size_t off = (size_t)(r0 + rr) * N + cc;
                if (EPI == 0) {
                    ((ushort*)Out)[off] = f2bf(v);
                } else if (EPI == 1) {
                    const float g = 1.0f / (1.0f + __expf(-v));
                    ((ushort*)Out)[off] = f2bf(g * bf2f(Aux[off]));
                } else {
                    ((float*)Out)[off] = v;
                }
            }
        }
    }
}

// ---------------- depthwise causal conv (K=4) + SiLU + fused dt ------------
// (round-4 version, measured ~21us)  Each block: 8 consecutive rows x 2048
// channels.  8 threads per head (aligned), dt reduce = 3 shfl_xor.
__global__ __launch_bounds__(256) void conv_silu_kernel(
    const ushort* __restrict__ proj, const float* __restrict__ cw,
    const float* __restrict__ cb, const float* __restrict__ dtw,
    const float* __restrict__ dtb, ushort* __restrict__ X,
    float* __restrict__ dt) {
    const int blk  = blockIdx.x;          // 2048 blocks
    const int half = blk & 1;
    const int tile = blk >> 1;            // 1024 tiles of 8 rows
    const int bl0  = tile * CROWS;
    const bool atStart = ((bl0 & (LSEQ - 1)) == 0);
    const int c0 = half * 2048 + threadIdx.x * 8;
    const int h  = c0 >> 6;               // head of this thread's 8 channels

    float4v w[8];
    const float4v* wp4 = (const float4v*)(cw + (size_t)c0 * 4);
#pragma unroll
    for (int t = 0; t < 8; t++) w[t] = wp4[t];
    float bias[8];
    const float4v b0 = *(const float4v*)(cb + c0);
    const float4v b1 = *(const float4v*)(cb + c0 + 4);
#pragma unroll
    for (int t = 0; t < 4; t++) { bias[t] = b0[t]; bias[t + 4] = b1[t]; }

    float dtwv[8];
    const float4v d0 = *(const float4v*)(dtw + c0);
    const float4v d1 = *(const float4v*)(dtw + c0 + 4);
#pragma unroll
    for (int t = 0; t < 4; t++) { dtwv[t] = d0[t]; dtwv[t + 4] = d1[t]; }
    const float dtbv = dtb[h];

    const size_t base = (size_t)bl0 * INNERC + c0;
    ushort8 w0, w1, w2;
    const ushort8 zz = {0, 0, 0, 0, 0, 0, 0, 0};
    if (atStart) {
        w0 = zz; w1 = zz; w2 = zz;
    } else {
        w0 = *(const ushort8*)(proj + base - 3 * (size_t)INNERC);
        w1 = *(const ushort8*)(proj + base - 2 * (size_t)INNERC);
        w2 = *(const ushort8*)(proj + base - 1 * (size_t)INNERC);
    }
#pragma unroll
    for (int r = 0; r < CROWS; r++) {
        const ushort8 cur = *(const ushort8*)(proj + base + (size_t)r * INNERC);
        ushort8 o;
        float dacc = 0.0f;
#pragma unroll
        for (int j = 0; j < 8; j++) {
            const float acc = bias[j]
                + w[j][0] * bf2f(w0[j]) + w[j][1] * bf2f(w1[j])
                + w[j][2] * bf2f(w2[j]) + w[j][3] * bf2f(cur[j]);
            const float s = acc / (1.0f + __expf(-acc));   // silu
            o[j] = f2bf(s);
            dacc += s * dtwv[j];
        }
        *(ushort8*)(X + base + (size_t)r * INNERC) = o;
        dacc += __shfl_xor(dacc, 1, 64);
        dacc += __shfl_xor(dacc, 2, 64);
        dacc += __shfl_xor(dacc, 4, 64);
        if ((threadIdx.x & 7) == 0) {
            const float z = dacc + dtbv;
            dt[(bl0 + r) * 64 + h] = (z > 20.0f) ? z : __logf(1.0f + __expf(z));
        }
        w0 = w1; w1 = w2; w2 = cur;
    }
}

// ---------------- chunked diagonal scan ----------------
__global__ __launch_bounds__(256) void scan_pass1(
    const ushort* __restrict__ X, const float* __restrict__ dt,
    const float* __restrict__ A_log, const float* __restrict__ Bv,
    float* __restrict__ sumP, float* __restrict__ sumS) {
    const int task = blockIdx.x * 4 + (threadIdx.x >> 6);
    const int p  = threadIdx.x & 63;
    const int ch = task & (NCHUNK - 1);
    const int bh = task >> 5;
    const int h  = bh & 63;
    const int b  = bh >> 6;
    const float Ac = -__expf(A_log[h * 64 + p]);
    const float Bc = Bv[h * 64 + p];
    float Pr = 1.0f, s = 0.0f;
    const int bl0 = b * LSEQ + ch * CHLEN;
#pragma unroll 4
    for (int i = 0; i < CHLEN; i++) {
        const int bl   = bl0 + i;
        const float dtv = dt[bl * 64 + h];
        const float x   = bf2f(X[(size_t)bl * INNERC + h * 64 + p]);
        const float a   = __expf(dtv * Ac);
        Pr *= a;
        s = a * s + dtv * Bc * x;
    }
    sumP[(size_t)task * 64 + p] = Pr;
    sumS[(size_t)task * 64 + p] = s;
}

// pass3 with inline carry: each task recomputes its chunk-prefix carry from
// sumP/sumS (<=31 fma pairs, L2-resident 2MB), replacing the separate pass2
// launch.  Then rescans the chunk and writes y = C*s + D*x.
__global__ __launch_bounds__(256) void scan_pass3(
    const ushort* __restrict__ X, const float* __restrict__ dt,
    const float* __restrict__ sumP, const float* __restrict__ sumS,
    const float* __restrict__ A_log, const float* __restrict__ Bv,
    const float* __restrict__ Cv, const float* __restrict__ Dv,
    ushort* __restrict__ Y) {
    const int task = blockIdx.x * 4 + (threadIdx.x >> 6);
    const int p  = threadIdx.x & 63;
    const int ch = task & (NCHUNK - 1);
    const int bh = task >> 5;
    const int h  = bh & 63;
    const int b  = bh >> 6;
    const float Ac = -__expf(A_log[h * 64 + p]);
    const float Bc = Bv[h * 64 + p];
    const float Cc = Cv[h * 64 + p];
    const float Dc = Dv[h * 64 + p];

    // carry = scan over earlier chunks of this (b,h)
    float s = 0.0f;
    for (int j = 0; j < ch; ++j) {
        const size_t idx = ((size_t)bh * NCHUNK + j) * 64 + p;
        s = sumP[idx] * s + sumS[idx];
    }

    const int bl0 = b * LSEQ + ch * CHLEN;
#pragma unroll 2
    for (int i = 0; i < CHLEN; i++) {
        const int bl = bl0 + i;
        const size_t xoff = (size_t)bl * INNERC + h * 64 + p;
        const float dtv = dt[bl * 64 + h];
        const float x   = bf2f(X[xoff]);
        const float a   = __expf(dtv * Ac);
        s = a * s + dtv * Bc * x;
        Y[xoff] = f2bf(Cc * s + Dc * x);
    }
}

// ---------------- workspace layout (bytes) ----------------
#define OFF_PROJ  ((size_t)0)            // 67,108,864 : proj -> Y -> comb
#define OFF_HID   ((size_t)67108864)     // 33,554,432 : hidden bf16
#define OFF_WB    ((size_t)100663296)    // 16,777,216 : weight bf16 (reused 3x)
#define OFF_DT    ((size_t)117440512)    //  2,097,152
#define OFF_SUMP  ((size_t)119537664)    //  1,048,576
#define OFF_SUMS  ((size_t)120586240)    //  1,048,576
#define OFF_CARRY ((size_t)121634816)    //  1,048,576 (unused; layout kept)
#define WS_NEEDED ((size_t)122683392)    // = 117 MiB

extern "C" void kernel_launch(void* const* d_in, const int* in_sizes, int n_in,
                              void* d_out, int out_size, void* d_ws, size_t ws_size,
                              hipStream_t stream) {
    if (ws_size < WS_NEEDED) {
        diag_kernel<<<1, 64, 0, stream>>>((float*)d_out, (float)(ws_size >> 20));
        return;
    }
    const float* hidden = (const float*)d_in[0];
    const float* w_in   = (const float*)d_in[1];
    const float* w_gate = (const float*)d_in[2];
    const float* w_out  = (const float*)d_in[3];
    const float* conv_w = (const float*)d_in[4];
    const float* conv_b = (const float*)d_in[5];
    const float* dt_w   = (const float*)d_in[6];
    const float* dt_b   = (const float*)d_in[7];
    const float* A_log  = (const float*)d_in[8];
    const float* Bv     = (const float*)d_in[9];
    const float* Cv     = (const float*)d_in[10];
    const float* Dv     = (const float*)d_in[11];

    char* ws = (char*)d_ws;
    ushort* projbuf = (ushort*)(ws + OFF_PROJ);   // proj, then Y, then comb
    ushort* hid16   = (ushort*)(ws + OFF_HID);
    ushort* wbuf    = (ushort*)(ws + OFF_WB);
    float*  dtf     = (float*)(ws + OFF_DT);
    float*  sumP    = (float*)(ws + OFF_SUMP);
    float*  sumS    = (float*)(ws + OFF_SUMS);
    ushort* x16     = (ushort*)d_out;             // X scratch inside d_out

    // hidden + in_proj weight casts in one launch
    cast2_bf16_kernel<<<12288, 256, 0, stream>>>(
        hidden, hid16, MROWS * DM, w_in, wbuf, INNERC * DM);

    // in_proj GEMM -> proj (bf16)
    gemm256<0><<<dim3(INNERC / 256, MROWS / 256), 512, 0, stream>>>(
        hid16, wbuf, projbuf, nullptr, MROWS, INNERC, DM);

    // conv + silu -> X (in d_out) with fused dt
    conv_silu_kernel<<<(MROWS / CROWS) * 2, 256, 0, stream>>>(
        projbuf, conv_w, conv_b, dt_w, dt_b, x16, dtf);

    // chunked scan; pass3 (with inline carry) writes y into projbuf
    scan_pass1<<<(NBATCH * NHH * NCHUNK) / 4, 256, 0, stream>>>(
        x16, dtf, A_log, Bv, sumP, sumS);
    scan_pass3<<<(NBATCH * NHH * NCHUNK) / 4, 256, 0, stream>>>(
        x16, dtf, sumP, sumS, A_log, Bv, Cv, Dv, projbuf);

    // gate GEMM with fused gating: comb = sigmoid(G) * Y, in-place in projbuf
    cast_bf16_kernel<<<4096, 256, 0, stream>>>(w_gate, wbuf, INNERC * DM);
    gemm256<1><<<dim3(INNERC / 256, MROWS / 256), 512, 0, stream>>>(
        hid16, wbuf, projbuf, projbuf, MROWS, INNERC, DM);

    // output projection (f32 out) — overwrites X scratch in d_out
    cast_bf16_kernel<<<4096, 256, 0, stream>>>(w_out, wbuf, DM * INNERC);
    gemm256<2><<<dim3(DM / 256, MROWS / 256), 512, 0, stream>>>(
        projbuf, wbuf, d_out, nullptr, MROWS, DM, INNERC);
}